// Round 1
// baseline (489.147 us; speedup 1.0000x reference)
//
#include <hip/hip_runtime.h>
#include <hip/hip_bf16.h>
#include <math.h>

#define BB 4
#define SS 4096
#define HH 2048
#define VOCAB 32000
#define NLC 8192
#define ROWS (BB*SS)
#define RPB 32

__device__ __forceinline__ float gelu_exact(float x) {
    return 0.5f * x * (1.0f + erff(x * 0.70710678118654752f));
}

// Step 2: winner = max lc index per position (numpy last-write-wins)
__global__ void scatter_win_kernel(const int* __restrict__ pos_b, const int* __restrict__ pos_s,
                                   int* __restrict__ win) {
    int i = blockIdx.x * blockDim.x + threadIdx.x;
    if (i < NLC) {
        int p = pos_b[i] * SS + pos_s[i];
        atomicMax(&win[p], i + 1);
    }
}

// Step 3: g2 = gelu( gelu( gelu(lc*W0+b0) @ W1 + b1 ) @ W2 + b2 )   [NLC x 64]
__global__ void mlp_g2_kernel(const float* __restrict__ lc, const float* __restrict__ W0,
                              const float* __restrict__ b0, const float* __restrict__ W1,
                              const float* __restrict__ b1, const float* __restrict__ W2,
                              const float* __restrict__ b2, float* __restrict__ g2out) {
    int w = threadIdx.x >> 6;      // wave id: one row per wave
    int j = threadIdx.x & 63;      // intermediate dim
    int row = blockIdx.x * 4 + w;
    __shared__ float g[4][64];
    float x = lc[row];
    float h = gelu_exact(fmaf(x, W0[j], b0[j]));
    g[w][j] = h;
    __syncthreads();
    float acc = b1[j];
#pragma unroll
    for (int k = 0; k < 64; ++k) acc = fmaf(g[w][k], W1[k * 64 + j], acc);
    acc = gelu_exact(acc);
    __syncthreads();               // WAR on g
    g[w][j] = acc;
    __syncthreads();
    float acc2 = b2[j];
#pragma unroll
    for (int k = 0; k < 64; ++k) acc2 = fmaf(g[w][k], W2[k * 64 + j], acc2);
    g2out[row * 64 + j] = gelu_exact(acc2);
}

// Step 4: feat = g2 @ Wout + bout for winner rows; scatter to out[p].
// 32 lc rows per block; Wout staged in LDS in 256-col chunks.
__global__ void feat_scatter_kernel(const float* __restrict__ g2, const int* __restrict__ win,
                                    const int* __restrict__ pos_b, const int* __restrict__ pos_s,
                                    const float* __restrict__ Wout, const float* __restrict__ bout,
                                    float* __restrict__ out) {
    __shared__ float wlds[64][256];   // 64 KiB: Wout[k][col-chunk]
    __shared__ float g2s[RPB][64];    // 8 KiB
    __shared__ int   wrow[RPB];       // dest row or -1
    int t = threadIdx.x;
    int base = blockIdx.x * RPB;

    for (int e = t; e < RPB * 64; e += 256) g2s[e >> 6][e & 63] = g2[base * 64 + e];
    if (t < RPB) {
        int i = base + t;
        int p = pos_b[i] * SS + pos_s[i];
        wrow[t] = (win[p] == i + 1) ? p : -1;
    }
    int w = t >> 6, l = t & 63;

    for (int c = 0; c < 8; ++c) {
        __syncthreads();  // WAR on wlds; first iter also covers g2s/wrow visibility
        for (int e4 = t; e4 < 64 * 64; e4 += 256) {
            int k = e4 >> 6, col4 = e4 & 63;
            *(float4*)&wlds[k][col4 * 4] = *(const float4*)&Wout[k * HH + c * 256 + col4 * 4];
        }
        __syncthreads();
        for (int rg = 0; rg < RPB / 4; ++rg) {
            int r = rg * 4 + w;       // wave-uniform row
            int p = wrow[r];
            if (p < 0) continue;      // uniform branch per wave
            float4 acc = *(const float4*)&bout[c * 256 + l * 4];
#pragma unroll
            for (int k = 0; k < 64; ++k) {
                float gk = g2s[r][k];                       // LDS broadcast
                float4 wv = *(const float4*)&wlds[k][l * 4]; // b128, conflict-free
                acc.x = fmaf(gk, wv.x, acc.x);
                acc.y = fmaf(gk, wv.y, acc.y);
                acc.z = fmaf(gk, wv.z, acc.z);
                acc.w = fmaf(gk, wv.w, acc.w);
            }
            *(float4*)&out[(size_t)p * HH + c * 256 + l * 4] = acc;
        }
    }
}

// Step 5: embedding gather for non-winner rows.
__global__ void gather_kernel(const int* __restrict__ ids, const int* __restrict__ win,
                              const float* __restrict__ wte, float* __restrict__ out) {
    int row = blockIdx.x;
    if (win[row] != 0) return;   // overwritten by feat_scatter
    int id = ids[row];
    id = id < 0 ? 0 : (id > VOCAB - 1 ? VOCAB - 1 : id);
    const float4* src = (const float4*)(wte + (size_t)id * HH);
    float4* dst = (float4*)(out + (size_t)row * HH);
    for (int e = threadIdx.x; e < HH / 4; e += 256) dst[e] = src[e];
}

extern "C" void kernel_launch(void* const* d_in, const int* in_sizes, int n_in,
                              void* d_out, int out_size, void* d_ws, size_t ws_size,
                              hipStream_t stream) {
    const int*   ids  = (const int*)d_in[0];
    const float* lc   = (const float*)d_in[1];
    const int*   pb   = (const int*)d_in[2];
    const int*   ps   = (const int*)d_in[3];
    const float* wte  = (const float*)d_in[4];
    const float* W0   = (const float*)d_in[5];
    const float* b0   = (const float*)d_in[6];
    const float* W1   = (const float*)d_in[7];
    const float* b1   = (const float*)d_in[8];
    const float* W2   = (const float*)d_in[9];
    const float* b2   = (const float*)d_in[10];
    const float* Wout = (const float*)d_in[11];
    const float* bout = (const float*)d_in[12];
    float* out = (float*)d_out;

    int*   win = (int*)d_ws;                                   // ROWS ints (64 KiB)
    float* g2  = (float*)((char*)d_ws + ROWS * sizeof(int));   // NLC*64 fp32 (2 MiB)

    hipMemsetAsync(win, 0, ROWS * sizeof(int), stream);
    scatter_win_kernel<<<NLC / 256, 256, 0, stream>>>(pb, ps, win);
    mlp_g2_kernel<<<NLC / 4, 256, 0, stream>>>(lc, W0, b0, W1, b1, W2, b2, g2);
    feat_scatter_kernel<<<NLC / RPB, 256, 0, stream>>>(g2, win, pb, ps, Wout, bout, out);
    gather_kernel<<<ROWS, 256, 0, stream>>>(ids, win, wte, out);
}

// Round 2
// 422.724 us; speedup vs baseline: 1.1571x; 1.1571x over previous
//
#include <hip/hip_runtime.h>
#include <hip/hip_bf16.h>
#include <math.h>

#define BB 4
#define SS 4096
#define HH 2048
#define VOCAB 32000
#define NLC 8192
#define ROWS (BB*SS)

// feat kernel tiling: 32 rows x 512 cols per block, 256 threads (4 waves)
#define FROWS 32
#define FCOLS 512

__device__ __forceinline__ float gelu_exact(float x) {
    return 0.5f * x * (1.0f + erff(x * 0.70710678118654752f));
}

// Step 2: winner = max lc index per position (numpy last-write-wins)
__global__ void scatter_win_kernel(const int* __restrict__ pos_b, const int* __restrict__ pos_s,
                                   int* __restrict__ win) {
    int i = blockIdx.x * blockDim.x + threadIdx.x;
    if (i < NLC) {
        int p = pos_b[i] * SS + pos_s[i];
        atomicMax(&win[p], i + 1);
    }
}

// Step 3: g2 = gelu( gelu( gelu(lc*W0+b0) @ W1 + b1 ) @ W2 + b2 )   [NLC x 64]
__global__ void mlp_g2_kernel(const float* __restrict__ lc, const float* __restrict__ W0,
                              const float* __restrict__ b0, const float* __restrict__ W1,
                              const float* __restrict__ b1, const float* __restrict__ W2,
                              const float* __restrict__ b2, float* __restrict__ g2out) {
    int w = threadIdx.x >> 6;      // wave id: one row per wave
    int j = threadIdx.x & 63;      // intermediate dim
    int row = blockIdx.x * 4 + w;
    __shared__ float g[4][64];
    float x = lc[row];
    float h = gelu_exact(fmaf(x, W0[j], b0[j]));
    g[w][j] = h;
    __syncthreads();
    float acc = b1[j];
#pragma unroll
    for (int k = 0; k < 64; ++k) acc = fmaf(g[w][k], W1[k * 64 + j], acc);
    acc = gelu_exact(acc);
    __syncthreads();               // WAR on g
    g[w][j] = acc;
    __syncthreads();
    float acc2 = b2[j];
#pragma unroll
    for (int k = 0; k < 64; ++k) acc2 = fmaf(g[w][k], W2[k * 64 + j], acc2);
    g2out[row * 64 + j] = gelu_exact(acc2);
}

// Step 4 (v2): feat = g2 @ Wout + bout, register-blocked, VALU-bound.
// Grid: (NLC/FROWS) x (HH/FCOLS) = 256 x 4 = 1024 blocks (4/CU).
// Wave w owns rows w*8..w*8+7 (wave-uniform => LDS broadcast reads).
// Lane l owns cols {cb + l*4 .. +3} and {cb + 256 + l*4 .. +3}.
__global__ void feat_scatter_kernel(const float* __restrict__ g2, const int* __restrict__ win,
                                    const int* __restrict__ pos_b, const int* __restrict__ pos_s,
                                    const float* __restrict__ Wout, const float* __restrict__ bout,
                                    float* __restrict__ out) {
    __shared__ float g2s[FROWS][64];   // 8 KiB
    __shared__ int   wrow[FROWS];      // dest row or -1
    int t = threadIdx.x;
    int rblk = blockIdx.x & 255;
    int cb   = (blockIdx.x >> 8) * FCOLS;
    int base = rblk * FROWS;

    // stage g2 tile (2048 floats) and winner rows
    {
        const float4* src = (const float4*)(g2 + base * 64);
        float4* dst = (float4*)&g2s[0][0];
        dst[t] = src[t];
        dst[t + 256] = src[t + 256];
    }
    if (t < FROWS) {
        int i = base + t;
        int p = pos_b[i] * SS + pos_s[i];
        wrow[t] = (win[p] == i + 1) ? p : -1;
    }
    __syncthreads();

    int w = t >> 6, l = t & 63;
    const float* wbase = Wout + cb + l * 4;

    float4 bv0 = *(const float4*)&bout[cb + l * 4];
    float4 bv1 = *(const float4*)&bout[cb + 256 + l * 4];
    float4 acc0[8], acc1[8];
#pragma unroll
    for (int r = 0; r < 8; ++r) { acc0[r] = bv0; acc1[r] = bv1; }

    for (int k0 = 0; k0 < 64; k0 += 4) {
        float4 wv0[4], wv1[4];
#pragma unroll
        for (int kk = 0; kk < 4; ++kk) {
            const float* wp = wbase + (size_t)(k0 + kk) * HH;
            wv0[kk] = *(const float4*)wp;
            wv1[kk] = *(const float4*)(wp + 256);
        }
#pragma unroll
        for (int r = 0; r < 8; ++r) {
            float4 gv = *(const float4*)&g2s[w * 8 + r][k0];  // wave-uniform addr: broadcast
#pragma unroll
            for (int c = 0; c < 4; ++c) {
                float g0 = (&gv.x)[0], g1 = (&gv.x)[1], g2v = (&gv.x)[2], g3 = (&gv.x)[3];
                (&acc0[r].x)[c] = fmaf(g0, (&wv0[0].x)[c],
                                  fmaf(g1, (&wv0[1].x)[c],
                                  fmaf(g2v, (&wv0[2].x)[c],
                                  fmaf(g3, (&wv0[3].x)[c], (&acc0[r].x)[c]))));
                (&acc1[r].x)[c] = fmaf(g0, (&wv1[0].x)[c],
                                  fmaf(g1, (&wv1[1].x)[c],
                                  fmaf(g2v, (&wv1[2].x)[c],
                                  fmaf(g3, (&wv1[3].x)[c], (&acc1[r].x)[c]))));
            }
        }
    }

#pragma unroll
    for (int r = 0; r < 8; ++r) {
        int p = wrow[w * 8 + r];          // wave-uniform
        if (p < 0) continue;
        float* op = out + (size_t)p * HH + cb + l * 4;
        *(float4*)op = acc0[r];
        *(float4*)(op + 256) = acc1[r];
    }
}

// Step 5: embedding gather for non-winner rows.
__global__ void gather_kernel(const int* __restrict__ ids, const int* __restrict__ win,
                              const float* __restrict__ wte, float* __restrict__ out) {
    int row = blockIdx.x;
    if (win[row] != 0) return;   // overwritten by feat_scatter
    int id = ids[row];
    id = id < 0 ? 0 : (id > VOCAB - 1 ? VOCAB - 1 : id);
    const float4* src = (const float4*)(wte + (size_t)id * HH);
    float4* dst = (float4*)(out + (size_t)row * HH);
    for (int e = threadIdx.x; e < HH / 4; e += 256) dst[e] = src[e];
}

extern "C" void kernel_launch(void* const* d_in, const int* in_sizes, int n_in,
                              void* d_out, int out_size, void* d_ws, size_t ws_size,
                              hipStream_t stream) {
    const int*   ids  = (const int*)d_in[0];
    const float* lc   = (const float*)d_in[1];
    const int*   pb   = (const int*)d_in[2];
    const int*   ps   = (const int*)d_in[3];
    const float* wte  = (const float*)d_in[4];
    const float* W0   = (const float*)d_in[5];
    const float* b0   = (const float*)d_in[6];
    const float* W1   = (const float*)d_in[7];
    const float* b1   = (const float*)d_in[8];
    const float* W2   = (const float*)d_in[9];
    const float* b2   = (const float*)d_in[10];
    const float* Wout = (const float*)d_in[11];
    const float* bout = (const float*)d_in[12];
    float* out = (float*)d_out;

    int*   win = (int*)d_ws;                                   // ROWS ints (64 KiB)
    float* g2  = (float*)((char*)d_ws + ROWS * sizeof(int));   // NLC*64 fp32 (2 MiB)

    hipMemsetAsync(win, 0, ROWS * sizeof(int), stream);
    scatter_win_kernel<<<NLC / 256, 256, 0, stream>>>(pb, ps, win);
    mlp_g2_kernel<<<NLC / 4, 256, 0, stream>>>(lc, W0, b0, W1, b1, W2, b2, g2);
    feat_scatter_kernel<<<(NLC / FROWS) * (HH / FCOLS), 256, 0, stream>>>(g2, win, pb, ps, Wout, bout, out);
    gather_kernel<<<ROWS, 256, 0, stream>>>(ids, win, wte, out);
}

// Round 4
// 412.297 us; speedup vs baseline: 1.1864x; 1.0253x over previous
//
#include <hip/hip_runtime.h>
#include <hip/hip_bf16.h>
#include <math.h>

#define BB 4
#define SS 4096
#define HH 2048
#define VOCAB 32000
#define NLC 8192
#define ROWS (BB*SS)

// feat tiling: 32 rows x 512 cols per block, 256 threads (4 waves)
#define FROWS 32
#define FCOLS 512
#define FEAT_BLOCKS ((NLC / FROWS) * (HH / FCOLS))   // 1024

typedef float fvec4 __attribute__((ext_vector_type(4)));   // native vec: OK for nontemporal builtins

__device__ __forceinline__ float gelu_exact(float x) {
    return 0.5f * x * (1.0f + erff(x * 0.70710678118654752f));
}

// Kernel B: fused scatter_win (blocks 0..31) + MLP chain -> g2 [NLC x 64]
__global__ void mlp_scatter_kernel(const float* __restrict__ lc, const float* __restrict__ W0,
                                   const float* __restrict__ b0, const float* __restrict__ W1,
                                   const float* __restrict__ b1, const float* __restrict__ W2,
                                   const float* __restrict__ b2, float* __restrict__ g2out,
                                   const int* __restrict__ pos_b, const int* __restrict__ pos_s,
                                   int* __restrict__ win) {
    int t = threadIdx.x;
    // winner = max lc index per position (numpy last-write-wins); device-scope atomic
    if (blockIdx.x < NLC / 256) {
        int i = blockIdx.x * 256 + t;
        int p = pos_b[i] * SS + pos_s[i];
        atomicMax(&win[p], i + 1);
    }

    int w = t >> 6;                // wave id: one row per wave
    int j = t & 63;                // intermediate dim
    int row = blockIdx.x * 4 + w;
    __shared__ float g[4][64];
    float x = lc[row];
    float h = gelu_exact(fmaf(x, W0[j], b0[j]));
    g[w][j] = h;
    __syncthreads();
    float acc = b1[j];
#pragma unroll
    for (int k = 0; k < 64; ++k) acc = fmaf(g[w][k], W1[k * 64 + j], acc);
    acc = gelu_exact(acc);
    __syncthreads();               // WAR on g
    g[w][j] = acc;
    __syncthreads();
    float acc2 = b2[j];
#pragma unroll
    for (int k = 0; k < 64; ++k) acc2 = fmaf(g[w][k], W2[k * 64 + j], acc2);
    g2out[row * 64 + j] = gelu_exact(acc2);
}

// Kernel C: fused feat-matmul-scatter (blocks 0..1023, VALU-bound) +
// embedding gather (blocks 1024.., HBM-bound). Complementary pipes overlap.
__global__ void feat_gather_kernel(const float* __restrict__ g2, const int* __restrict__ win,
                                   const int* __restrict__ pos_b, const int* __restrict__ pos_s,
                                   const float* __restrict__ Wout, const float* __restrict__ bout,
                                   const int* __restrict__ ids, const float* __restrict__ wte,
                                   float* __restrict__ out) {
    __shared__ float g2s[FROWS][64];   // 8 KiB (feat path only)
    __shared__ int   wrow[FROWS];
    int t = threadIdx.x;

    if (blockIdx.x >= FEAT_BLOCKS) {
        // ---- gather path: one output row per block ----
        int row = blockIdx.x - FEAT_BLOCKS;
        if (win[row] > 0) return;          // overwritten by feat path
        int id = ids[row];
        id = id < 0 ? 0 : (id > VOCAB - 1 ? VOCAB - 1 : id);
        const fvec4* src = (const fvec4*)(wte + (size_t)id * HH);
        fvec4* dst = (fvec4*)(out + (size_t)row * HH);
        // out is write-once, never re-read: nontemporal to spare L2/L3 for wte
        fvec4 v0 = src[t];
        fvec4 v1 = src[t + 256];
        __builtin_nontemporal_store(v0, &dst[t]);
        __builtin_nontemporal_store(v1, &dst[t + 256]);
        return;
    }

    // ---- feat path: 32 rows x 512 cols register-blocked matmul + scatter ----
    int rblk = blockIdx.x & 255;
    int cb   = (blockIdx.x >> 8) * FCOLS;
    int base = rblk * FROWS;

    {
        const float4* src = (const float4*)(g2 + base * 64);
        float4* dst = (float4*)&g2s[0][0];
        dst[t] = src[t];
        dst[t + 256] = src[t + 256];
    }
    if (t < FROWS) {
        int i = base + t;
        int p = pos_b[i] * SS + pos_s[i];
        wrow[t] = (win[p] == i + 1) ? p : -1;
    }
    __syncthreads();

    int w = t >> 6, l = t & 63;
    const float* wbase = Wout + cb + l * 4;

    float4 bv0 = *(const float4*)&bout[cb + l * 4];
    float4 bv1 = *(const float4*)&bout[cb + 256 + l * 4];
    float4 acc0[8], acc1[8];
#pragma unroll
    for (int r = 0; r < 8; ++r) { acc0[r] = bv0; acc1[r] = bv1; }

    for (int k0 = 0; k0 < 64; k0 += 4) {
        float4 wv0[4], wv1[4];
#pragma unroll
        for (int kk = 0; kk < 4; ++kk) {
            const float* wp = wbase + (size_t)(k0 + kk) * HH;
            wv0[kk] = *(const float4*)wp;
            wv1[kk] = *(const float4*)(wp + 256);
        }
#pragma unroll
        for (int r = 0; r < 8; ++r) {
            float4 gv = *(const float4*)&g2s[w * 8 + r][k0];  // wave-uniform: LDS broadcast
#pragma unroll
            for (int c = 0; c < 4; ++c) {
                float g0 = (&gv.x)[0], g1 = (&gv.x)[1], g2v = (&gv.x)[2], g3 = (&gv.x)[3];
                (&acc0[r].x)[c] = fmaf(g0, (&wv0[0].x)[c],
                                  fmaf(g1, (&wv0[1].x)[c],
                                  fmaf(g2v, (&wv0[2].x)[c],
                                  fmaf(g3, (&wv0[3].x)[c], (&acc0[r].x)[c]))));
                (&acc1[r].x)[c] = fmaf(g0, (&wv1[0].x)[c],
                                  fmaf(g1, (&wv1[1].x)[c],
                                  fmaf(g2v, (&wv1[2].x)[c],
                                  fmaf(g3, (&wv1[3].x)[c], (&acc1[r].x)[c]))));
            }
        }
    }

#pragma unroll
    for (int r = 0; r < 8; ++r) {
        int p = wrow[w * 8 + r];          // wave-uniform
        if (p < 0) continue;
        float* op = out + (size_t)p * HH + cb + l * 4;
        *(float4*)op = acc0[r];
        *(float4*)(op + 256) = acc1[r];
    }
}

extern "C" void kernel_launch(void* const* d_in, const int* in_sizes, int n_in,
                              void* d_out, int out_size, void* d_ws, size_t ws_size,
                              hipStream_t stream) {
    const int*   ids  = (const int*)d_in[0];
    const float* lc   = (const float*)d_in[1];
    const int*   pb   = (const int*)d_in[2];
    const int*   ps   = (const int*)d_in[3];
    const float* wte  = (const float*)d_in[4];
    const float* W0   = (const float*)d_in[5];
    const float* b0   = (const float*)d_in[6];
    const float* W1   = (const float*)d_in[7];
    const float* b1   = (const float*)d_in[8];
    const float* W2   = (const float*)d_in[9];
    const float* b2   = (const float*)d_in[10];
    const float* Wout = (const float*)d_in[11];
    const float* bout = (const float*)d_in[12];
    float* out = (float*)d_out;

    int*   win = (int*)d_ws;                                   // ROWS ints (64 KiB)
    float* g2  = (float*)((char*)d_ws + ROWS * sizeof(int));   // NLC*64 fp32 (2 MiB)

    (void)hipMemsetAsync(win, 0, ROWS * sizeof(int), stream);
    mlp_scatter_kernel<<<NLC / 4, 256, 0, stream>>>(lc, W0, b0, W1, b1, W2, b2, g2, pb, ps, win);
    feat_gather_kernel<<<FEAT_BLOCKS + ROWS, 256, 0, stream>>>(g2, win, pb, ps, Wout, bout, ids, wte, out);
}